// Round 1
// baseline (17776.053 us; speedup 1.0000x reference)
//
#include <hip/hip_runtime.h>
#include <hip/hip_bf16.h>

#define VOCAB 200000
#define EMB 256
#define HID 512
#define SEQ 8192
#define TOK 32768
#define TAGS 512
#define G4H 2048  // 4*HID

#define SENT 0x7FBFFFFFu  // NaN payload sentinel; real h is always finite (bounded by tanh/sigmoid)

__device__ __forceinline__ float sigmoidf_(float x) { return 1.0f / (1.0f + __expf(-x)); }
__device__ __forceinline__ float tanhf_(float x) { return 1.0f - 2.0f / (1.0f + __expf(2.0f * x)); }

// ---------------- kernel 0: sentinel init for h double-buffer ----------------
__global__ void init_sentinel(unsigned* __restrict__ hbuf, int n) {
  int i = blockIdx.x * blockDim.x + threadIdx.x;
  int stride = gridDim.x * blockDim.x;
  for (; i < n; i += stride) hbuf[i] = SENT;
}

// ---------------- kernel 1: embedding bag (sum pool per sorted segment) ------
__global__ __launch_bounds__(256) void embed_pool(
    const float* __restrict__ emb, const int* __restrict__ ids,
    const int* __restrict__ seg, float* __restrict__ out) {
  int s = blockIdx.x;
  int d = threadIdx.x;  // 256 = EMB
  // lower bound: first idx with seg[idx] >= s
  int lo = 0, hi = TOK;
  while (lo < hi) { int m = (lo + hi) >> 1; if (seg[m] < s) lo = m + 1; else hi = m; }
  int start = lo;
  hi = TOK;
  while (lo < hi) { int m = (lo + hi) >> 1; if (seg[m] < s + 1) lo = m + 1; else hi = m; }
  int end = lo;
  float acc = 0.f;
  for (int tkn = start; tkn < end; ++tkn) {
    acc += emb[(long)ids[tkn] * EMB + d];
  }
  out[s * EMB + d] = acc;
}

// ---------------- kernel 2: xg = embeds @ w_ih^T + b  (both dirs) ------------
// A: embeds [SEQ][256], B: w_ih [2048][256], C: xg [2][SEQ][2048]
__global__ __launch_bounds__(256) void xg_gemm(
    const float* __restrict__ embeds,
    const float* __restrict__ w_ih_f, const float* __restrict__ b_f,
    const float* __restrict__ w_ih_b, const float* __restrict__ b_b,
    float* __restrict__ xg) {
  int dir = blockIdx.z;
  const float* W = dir ? w_ih_b : w_ih_f;
  const float* B = dir ? b_b : b_f;
  float* out = xg + (size_t)dir * SEQ * G4H;
  int j0 = blockIdx.x * 64, t0 = blockIdx.y * 64;
  __shared__ float As[64][65];
  __shared__ float Bs[64][65];
  int tid = threadIdx.x;
  int ty = tid >> 4, tx = tid & 15;
  float acc[4][4] = {};
  for (int kc = 0; kc < EMB; kc += 64) {
#pragma unroll
    for (int i = 0; i < 4; ++i) {
      int fi = tid * 4 + i;          // 0..1023
      int r = fi >> 4, c4 = fi & 15; // row 0..63, f4 col 0..15
      float4 a = *(const float4*)&embeds[(size_t)(t0 + r) * EMB + kc + c4 * 4];
      As[r][c4 * 4 + 0] = a.x; As[r][c4 * 4 + 1] = a.y;
      As[r][c4 * 4 + 2] = a.z; As[r][c4 * 4 + 3] = a.w;
      float4 b = *(const float4*)&W[(size_t)(j0 + r) * EMB + kc + c4 * 4];
      Bs[r][c4 * 4 + 0] = b.x; Bs[r][c4 * 4 + 1] = b.y;
      Bs[r][c4 * 4 + 2] = b.z; Bs[r][c4 * 4 + 3] = b.w;
    }
    __syncthreads();
#pragma unroll 8
    for (int kk = 0; kk < 64; ++kk) {
      float a[4], b[4];
#pragma unroll
      for (int i = 0; i < 4; ++i) a[i] = As[ty * 4 + i][kk];
#pragma unroll
      for (int i = 0; i < 4; ++i) b[i] = Bs[tx * 4 + i][kk];
#pragma unroll
      for (int i = 0; i < 4; ++i)
#pragma unroll
        for (int j = 0; j < 4; ++j) acc[i][j] = fmaf(a[i], b[j], acc[i][j]);
    }
    __syncthreads();
  }
#pragma unroll
  for (int i = 0; i < 4; ++i)
#pragma unroll
    for (int j = 0; j < 4; ++j)
      out[(size_t)(t0 + ty * 4 + i) * G4H + j0 + tx * 4 + j] = acc[i][j] + B[j0 + tx * 4 + j];
}

// ---------------- kernel 3: persistent bidirectional LSTM scan ---------------
// 64 WGs: dir = wg>>5, group g = wg&31 owns h indices [16g,16g+16) -> 64 gate rows.
// Weights in VGPRs: thread covers 8 rows x 16 cols. h broadcast via LDS,
// partial sums reduced by shfl_xor within 32-lane halves.
__global__ __launch_bounds__(256, 1) void lstm_scan(
    const float* __restrict__ w_hh_f, const float* __restrict__ w_hh_b,
    const float* __restrict__ xg, unsigned* __restrict__ hbuf) {
  int wg = blockIdx.x;
  int dir = wg >> 5;
  int g = wg & 31;
  const float* W = dir ? w_hh_b : w_hh_f;
  const float* xgd = xg + (size_t)dir * SEQ * G4H;
  unsigned* hb = hbuf + (size_t)dir * SEQ * HID;

  int tid = threadIdx.x;
  int w = tid >> 6;       // gate type 0..3 (i,f,g,o)
  int lane = tid & 63;
  int half = lane >> 5;   // 0..1
  int cb = lane & 31;     // column block
  int c0 = cb * 16;

  // preload weight slice into registers: rows k = half + 2j, global 512w + 16g + k
  float wreg[8][16];
#pragma unroll
  for (int j = 0; j < 8; ++j) {
    int row = 512 * w + 16 * g + half + 2 * j;
    const float* wr = &W[(size_t)row * HID + c0];
#pragma unroll
    for (int q = 0; q < 4; ++q) {
      float4 v = *(const float4*)&wr[q * 4];
      wreg[j][q * 4 + 0] = v.x; wreg[j][q * 4 + 1] = v.y;
      wreg[j][q * 4 + 2] = v.z; wreg[j][q * 4 + 3] = v.w;
    }
  }

  __shared__ float h_lds[HID];
  __shared__ float gates[64];

  float cstate = 0.f;           // live in tid<16 only
  const int khid = 16 * g + tid; // h index for tid<16

  for (int t = 0; t < SEQ; ++t) {
    int tt = dir ? (SEQ - 1 - t) : t;
    // prefetch xg rows for owner lanes (cb==0)
    float xgp[8];
    if (cb == 0) {
#pragma unroll
      for (int j = 0; j < 8; ++j)
        xgp[j] = xgd[(size_t)tt * G4H + 512 * w + 16 * g + half + 2 * j];
    }
    // stage h_prev into LDS (sentinel-poll)
    if (t == 0) {
      h_lds[2 * tid] = 0.f;
      h_lds[2 * tid + 1] = 0.f;
    } else {
      int pt = dir ? (tt + 1) : (tt - 1);
      unsigned* src = hb + (size_t)pt * HID + 2 * tid;
      unsigned v0 = __hip_atomic_load(&src[0], __ATOMIC_RELAXED, __HIP_MEMORY_SCOPE_AGENT);
      int gd = 0;
      while (v0 == SENT && ++gd < (1 << 22)) {
        __builtin_amdgcn_s_sleep(1);
        v0 = __hip_atomic_load(&src[0], __ATOMIC_RELAXED, __HIP_MEMORY_SCOPE_AGENT);
      }
      unsigned v1 = __hip_atomic_load(&src[1], __ATOMIC_RELAXED, __HIP_MEMORY_SCOPE_AGENT);
      gd = 0;
      while (v1 == SENT && ++gd < (1 << 22)) {
        __builtin_amdgcn_s_sleep(1);
        v1 = __hip_atomic_load(&src[1], __ATOMIC_RELAXED, __HIP_MEMORY_SCOPE_AGENT);
      }
      h_lds[2 * tid] = __uint_as_float(v0);
      h_lds[2 * tid + 1] = __uint_as_float(v1);
    }
    __syncthreads();  // [A] h_lds ready

    // matvec: 8 rows x 16 cols per thread
    float hv[16];
#pragma unroll
    for (int c = 0; c < 16; ++c) hv[c] = h_lds[c0 + c];
    float s[8];
#pragma unroll
    for (int j = 0; j < 8; ++j) {
      float a = 0.f;
#pragma unroll
      for (int c = 0; c < 16; ++c) a = fmaf(wreg[j][c], hv[c], a);
      s[j] = a;
    }
    // reduce across the 32 column blocks (within each 32-lane half)
#pragma unroll
    for (int j = 0; j < 8; ++j) {
      s[j] += __shfl_xor(s[j], 1);
      s[j] += __shfl_xor(s[j], 2);
      s[j] += __shfl_xor(s[j], 4);
      s[j] += __shfl_xor(s[j], 8);
      s[j] += __shfl_xor(s[j], 16);
    }
    if (cb == 0) {
#pragma unroll
      for (int j = 0; j < 8; ++j)
        gates[w * 16 + half + 2 * j] = s[j] + xgp[j];
    }
    __syncthreads();  // [B] gates ready

    if (tid < 16) {
      float gi = gates[tid], gf = gates[16 + tid], gg = gates[32 + tid], go = gates[48 + tid];
      float iv = sigmoidf_(gi), fv = sigmoidf_(gf), gv = tanhf_(gg), ov = sigmoidf_(go);
      cstate = fv * cstate + iv * gv;
      float hval = ov * tanhf_(cstate);
      __hip_atomic_store(hb + (size_t)tt * HID + khid, __float_as_uint(hval),
                         __ATOMIC_RELAXED, __HIP_MEMORY_SCOPE_AGENT);
    }
  }
}

// ---------------- kernel 4: logits = h_cat @ w_out^T + b_out -----------------
// h_cat[t] = [h_fwd[t] (512) | h_bwd[t] (512)]; w_out [512][1024]
__global__ __launch_bounds__(256) void out_gemm(
    const unsigned* __restrict__ hbuf, const float* __restrict__ w_out,
    const float* __restrict__ b_out, float* __restrict__ out) {
  int j0 = blockIdx.x * 128, t0 = blockIdx.y * 64;
  __shared__ float hs[64][65];
  __shared__ float ws_[128][65];
  int tid = threadIdx.x;
  int ti = tid & 15, ji = tid >> 4;
  float acc[4][8] = {};
  const float* hf = (const float*)hbuf;
  for (int kc = 0; kc < 1024; kc += 64) {
    const float* hsrc = (kc < 512) ? hf : (hf + (size_t)SEQ * HID);
    int kb = kc & 511;
#pragma unroll
    for (int i = 0; i < 4; ++i) {
      int fi = tid * 4 + i;
      int r = fi >> 4, c4 = fi & 15;
      float4 v = *(const float4*)&hsrc[(size_t)(t0 + r) * HID + kb + c4 * 4];
      hs[r][c4 * 4 + 0] = v.x; hs[r][c4 * 4 + 1] = v.y;
      hs[r][c4 * 4 + 2] = v.z; hs[r][c4 * 4 + 3] = v.w;
    }
#pragma unroll
    for (int i = 0; i < 8; ++i) {
      int fi = tid * 8 + i;
      int r = fi >> 4, c4 = fi & 15;
      float4 v = *(const float4*)&w_out[(size_t)(j0 + r) * 1024 + kc + c4 * 4];
      ws_[r][c4 * 4 + 0] = v.x; ws_[r][c4 * 4 + 1] = v.y;
      ws_[r][c4 * 4 + 2] = v.z; ws_[r][c4 * 4 + 3] = v.w;
    }
    __syncthreads();
#pragma unroll 4
    for (int kk = 0; kk < 64; ++kk) {
      float a[4], b[8];
#pragma unroll
      for (int x = 0; x < 4; ++x) a[x] = hs[ti * 4 + x][kk];
#pragma unroll
      for (int y = 0; y < 8; ++y) b[y] = ws_[ji * 8 + y][kk];
#pragma unroll
      for (int x = 0; x < 4; ++x)
#pragma unroll
        for (int y = 0; y < 8; ++y) acc[x][y] = fmaf(a[x], b[y], acc[x][y]);
    }
    __syncthreads();
  }
#pragma unroll
  for (int x = 0; x < 4; ++x)
#pragma unroll
    for (int y = 0; y < 8; ++y)
      out[(size_t)(t0 + ti * 4 + x) * TAGS + j0 + ji * 8 + y] = acc[x][y] + b_out[j0 + ji * 8 + y];
}

// ---------------- kernel 5: row-wise log_softmax in place --------------------
__global__ __launch_bounds__(256) void logsoftmax(float* __restrict__ out) {
  int t = blockIdx.x;
  float* row = out + (size_t)t * TAGS;
  int tid = threadIdx.x;
  float a = row[tid], b = row[tid + 256];
  float m = fmaxf(a, b);
  m = fmaxf(m, __shfl_xor(m, 1));
  m = fmaxf(m, __shfl_xor(m, 2));
  m = fmaxf(m, __shfl_xor(m, 4));
  m = fmaxf(m, __shfl_xor(m, 8));
  m = fmaxf(m, __shfl_xor(m, 16));
  m = fmaxf(m, __shfl_xor(m, 32));
  __shared__ float redm[4];
  __shared__ float reds[4];
  int wv = tid >> 6;
  if ((tid & 63) == 0) redm[wv] = m;
  __syncthreads();
  m = fmaxf(fmaxf(redm[0], redm[1]), fmaxf(redm[2], redm[3]));
  float s = __expf(a - m) + __expf(b - m);
  s += __shfl_xor(s, 1);
  s += __shfl_xor(s, 2);
  s += __shfl_xor(s, 4);
  s += __shfl_xor(s, 8);
  s += __shfl_xor(s, 16);
  s += __shfl_xor(s, 32);
  if ((tid & 63) == 0) reds[wv] = s;
  __syncthreads();
  s = reds[0] + reds[1] + reds[2] + reds[3];
  float ls = m + __logf(s);
  row[tid] = a - ls;
  row[tid + 256] = b - ls;
}

extern "C" void kernel_launch(void* const* d_in, const int* in_sizes, int n_in,
                              void* d_out, int out_size, void* d_ws, size_t ws_size,
                              hipStream_t stream) {
  (void)in_sizes; (void)n_in; (void)out_size; (void)ws_size;
  const float* emb    = (const float*)d_in[0];
  const float* w_ih_f = (const float*)d_in[1];
  const float* w_hh_f = (const float*)d_in[2];
  const float* b_f    = (const float*)d_in[3];
  const float* w_ih_b = (const float*)d_in[4];
  const float* w_hh_b = (const float*)d_in[5];
  const float* b_b    = (const float*)d_in[6];
  const float* w_out  = (const float*)d_in[7];
  const float* b_out  = (const float*)d_in[8];
  const int*   ids    = (const int*)d_in[9];
  const int*   seg    = (const int*)d_in[10];
  float* out = (float*)d_out;

  char* ws = (char*)d_ws;
  float*    embeds = (float*)ws;                                       // 8 MB
  float*    xg     = (float*)(ws + (8ll << 20));                       // 128 MB
  unsigned* hbuf   = (unsigned*)(ws + (8ll << 20) + (128ll << 20));    // 32 MB

  init_sentinel<<<2048, 256, 0, stream>>>(hbuf, 2 * SEQ * HID);
  embed_pool<<<SEQ, 256, 0, stream>>>(emb, ids, seg, embeds);
  dim3 g2(G4H / 64, SEQ / 64, 2);
  xg_gemm<<<g2, 256, 0, stream>>>(embeds, w_ih_f, b_f, w_ih_b, b_b, xg);
  lstm_scan<<<64, 256, 0, stream>>>(w_hh_f, w_hh_b, xg, hbuf);
  dim3 g4(TAGS / 128, SEQ / 64);
  out_gemm<<<g4, 256, 0, stream>>>(hbuf, w_out, b_out, out);
  logsoftmax<<<SEQ, 256, 0, stream>>>(out);
}